// Round 4
// baseline (623.733 us; speedup 1.0000x reference)
//
#include <hip/hip_runtime.h>
#include <stdint.h>

#define SEQ 2048
#define HID 4096
#define NH 32
#define HD 128

static constexpr float ATT_SCALE = 0.08838834764831845f; // 128^-0.5
static constexpr float L2E = 1.4426950408889634f;

typedef short bf16x8 __attribute__((ext_vector_type(8)));
typedef float f32x4 __attribute__((ext_vector_type(4)));

__device__ __forceinline__ unsigned short f2bf(float f) {
  union { float f; unsigned int u; } v; v.f = f;
  unsigned int u = v.u + 0x7FFFu + ((v.u >> 16) & 1u);
  return (unsigned short)(u >> 16);
}

__device__ __forceinline__ void gl_lds16(const void* g, void* l) {
  __builtin_amdgcn_global_load_lds((const __attribute__((address_space(1))) void*)g,
                                   (__attribute__((address_space(3))) void*)l, 16, 0, 0);
}

// ---------------- pre-pass: hidden f32 -> bf16 ----------------
__global__ void k_conv_hidden(const float* __restrict__ x, unsigned short* __restrict__ y) {
  int i = blockIdx.x * 256 + threadIdx.x;   // 8 elems per thread
  const float4* p = (const float4*)x;
  float4 a = p[(size_t)i * 2];
  float4 b = p[(size_t)i * 2 + 1];
  bf16x8 o;
  o[0] = (short)f2bf(a.x); o[1] = (short)f2bf(a.y); o[2] = (short)f2bf(a.z); o[3] = (short)f2bf(a.w);
  o[4] = (short)f2bf(b.x); o[5] = (short)f2bf(b.y); o[6] = (short)f2bf(b.z); o[7] = (short)f2bf(b.w);
  *(bf16x8*)(y + (size_t)i * 8) = o;
}

// ---------------- pre-pass: W [K][N] f32 -> WT [N][K] bf16 ----------------
__global__ void k_transpose_w(const float* __restrict__ W, unsigned short* __restrict__ WT,
                              int Kd, int Nd) {
  __shared__ float t[64][65];
  int nb = Nd >> 6;
  int bk = blockIdx.x / nb, bn = blockIdx.x % nb;
  int c = threadIdx.x & 63, r = threadIdx.x >> 6;
  const float* src = W + (size_t)(bk * 64) * Nd + bn * 64 + c;
#pragma unroll
  for (int i = 0; i < 16; ++i) { int kk = r + i * 4; t[kk][c] = src[(size_t)kk * Nd]; }
  __syncthreads();
  unsigned short* dst = WT + (size_t)(bn * 64) * Kd + bk * 64 + c;
#pragma unroll
  for (int i = 0; i < 16; ++i) { int nn = r + i * 4; dst[(size_t)nn * Kd] = f2bf(t[c][nn]); }
}

// ---------------- V [h][s][d] -> VT [h][d][s] (bf16) ----------------
__global__ void k_transpose_v(const unsigned short* __restrict__ V, unsigned short* __restrict__ VT) {
  __shared__ unsigned short t[64][72];
  int b = blockIdx.x;
  int dblk = b & 1, sblk = (b >> 1) & 31, h = b >> 6;
  int c = threadIdx.x & 63, r = threadIdx.x >> 6;
  const unsigned short* src = V + ((size_t)(h * SEQ + sblk * 64)) * HD + dblk * 64 + c;
#pragma unroll
  for (int i = 0; i < 16; ++i) { int ss = r + i * 4; t[ss][c] = src[(size_t)ss * HD]; }
  __syncthreads();
  unsigned short* dst = VT + ((size_t)(h * HD + dblk * 64)) * SEQ + sblk * 64 + c;
#pragma unroll
  for (int i = 0; i < 16; ++i) { int dd = r + i * 4; dst[(size_t)dd * SEQ] = t[c][dd]; }
}

// ======== deep-pipelined GEMM: C[M][N] = A[M][K] @ BT[N][K]^T + bias ========
// BM=128 BN=256 BK=64, 8 waves (2M x 4N), per-wave 64x64 output.
// LDS layout: A [2 buf][2 kh][128 rows][32 k]  (buf stride 16384, kh 8192)
//             B [2 buf][2 kh][256 cols][32 k]  (buf stride 32768, kh 16384)
// K-split halves give conflict-free contiguous-stripe ds_read_b128 and
// linear global_load_lds staging (no swizzle anywhere). Counted vmcnt(6)
// keeps 6 staging loads in flight across every barrier (never drains to 0).
template <int EPI>
__global__ __launch_bounds__(512, 2)
void k_gemm8(const unsigned short* __restrict__ A, const unsigned short* __restrict__ BT,
             const float* __restrict__ bias, const int* __restrict__ posids,
             float* __restrict__ outF, unsigned short* __restrict__ Qo,
             unsigned short* __restrict__ Ko, unsigned short* __restrict__ Vo, int N) {
  constexpr int K = 4096;
  constexpr int NT = K / 64;
  __shared__ __align__(16) char Als[32768];
  __shared__ __align__(16) char Bls[65536];
  const int tid = threadIdx.x;
  const int lane = tid & 63, wave = tid >> 6;
  const int wm = wave >> 2, wn = wave & 3;
  const int nbn = N >> 8;
  const int wg = ((blockIdx.x & 7) * ((int)gridDim.x >> 3)) + ((int)blockIdx.x >> 3);
  const int bm = wg / nbn, bn = wg % nbn;
  const int m0 = bm << 7, n0 = bn << 8;
  const int lrow = lane & 15;
  const int lk16 = (lane >> 4) << 4;                 // 16-B chunk within 64-B row
  const int aOff = (wm * 64 + lrow) * 64 + lk16;     // within one A kh region
  const int bOff = (wn * 64 + lrow) * 64 + lk16;     // within one B kh region

  // staging: per kh, A = 1 load/thread (128 rows x 32k), B = 2 loads (256 cols)
  const char* aSrc = (const char*)A + (size_t)(m0 + (tid >> 2)) * (K * 2) + (tid & 3) * 16;
  const char* bSrc0 = (const char*)BT + (size_t)(n0 + (tid >> 2)) * (K * 2) + (tid & 3) * 16;
  const char* bSrc1 = bSrc0 + (size_t)128 * (K * 2);
  char* aD = Als + tid * 16;
  char* bD = Bls + tid * 16;

#define STG_A(tt, h, bb) gl_lds16(aSrc + (size_t)(tt) * 128 + (h) * 64, aD + (bb) * 16384 + (h) * 8192)
#define STG_B(tt, h, bb) do { \
    gl_lds16(bSrc0 + (size_t)(tt) * 128 + (h) * 64, bD + (bb) * 32768 + (h) * 16384);        \
    gl_lds16(bSrc1 + (size_t)(tt) * 128 + (h) * 64, bD + (bb) * 32768 + (h) * 16384 + 8192); \
  } while (0)

  f32x4 acc[4][4] = {};

  // prologue: stage 0.kh0, 0.kh1, 1.kh0 (9 loads); gate 0.kh0 (oldest 3)
  STG_A(0, 0, 0); STG_B(0, 0, 0);
  STG_A(0, 1, 0); STG_B(0, 1, 0);
  STG_A(1, 0, 1); STG_B(1, 0, 1);
  asm volatile("s_waitcnt vmcnt(6)" ::: "memory");
  __builtin_amdgcn_s_barrier();

  for (int t = 0; t < NT; ++t) {
    const int b = t & 1;
    const char* Ab = Als + b * 16384;
    const char* Bb = Bls + b * 32768;
    bf16x8 af[4], bfr[4];

    // ---------- phase 1 (kk=0): read kh0, stage (t+1).kh1 ----------
#pragma unroll
    for (int mi = 0; mi < 4; ++mi) af[mi] = *(const bf16x8*)(Ab + aOff + mi * 1024);
#pragma unroll
    for (int ni = 0; ni < 4; ++ni) bfr[ni] = *(const bf16x8*)(Bb + bOff + ni * 1024);
    { const int t1 = (t + 1) & (NT - 1); const int b1 = b ^ 1;
      STG_A(t1, 1, b1); STG_B(t1, 1, b1); }
    __builtin_amdgcn_s_barrier();
    asm volatile("s_waitcnt lgkmcnt(0)" ::: "memory");
    __builtin_amdgcn_sched_barrier(0);
    __builtin_amdgcn_s_setprio(1);
#pragma unroll
    for (int mi = 0; mi < 4; ++mi)
#pragma unroll
      for (int ni = 0; ni < 4; ++ni)
        acc[mi][ni] = __builtin_amdgcn_mfma_f32_16x16x32_bf16(af[mi], bfr[ni], acc[mi][ni], 0, 0, 0);
    __builtin_amdgcn_s_setprio(0);
    asm volatile("s_waitcnt vmcnt(6)" ::: "memory");   // gate t.kh1
    __builtin_amdgcn_s_barrier();

    // ---------- phase 2 (kk=1): read kh1, stage (t+2).kh0 ----------
#pragma unroll
    for (int mi = 0; mi < 4; ++mi) af[mi] = *(const bf16x8*)(Ab + 8192 + aOff + mi * 1024);
#pragma unroll
    for (int ni = 0; ni < 4; ++ni) bfr[ni] = *(const bf16x8*)(Bb + 16384 + bOff + ni * 1024);
    { const int t2 = (t + 2) & (NT - 1);
      STG_A(t2, 0, b); STG_B(t2, 0, b); }
    __builtin_amdgcn_s_barrier();
    asm volatile("s_waitcnt lgkmcnt(0)" ::: "memory");
    __builtin_amdgcn_sched_barrier(0);
    __builtin_amdgcn_s_setprio(1);
#pragma unroll
    for (int mi = 0; mi < 4; ++mi)
#pragma unroll
      for (int ni = 0; ni < 4; ++ni)
        acc[mi][ni] = __builtin_amdgcn_mfma_f32_16x16x32_bf16(af[mi], bfr[ni], acc[mi][ni], 0, 0, 0);
    __builtin_amdgcn_s_setprio(0);
    asm volatile("s_waitcnt vmcnt(6)" ::: "memory");   // gate (t+1).kh0
    __builtin_amdgcn_s_barrier();
  }
#undef STG_A
#undef STG_B

  const int rb = (lane >> 4) << 2;
  float bcol[4];
#pragma unroll
  for (int ni = 0; ni < 4; ++ni) bcol[ni] = bias[n0 + wn * 64 + ni * 16 + lrow];

  if (EPI == 0) {
#pragma unroll
    for (int mi = 0; mi < 4; ++mi) {
      int sBase = m0 + wm * 64 + mi * 16 + rb;
#pragma unroll
      for (int reg = 0; reg < 4; ++reg) {
        int s = sBase + reg;
        float* orow = outF + (size_t)s * N + n0 + wn * 64 + lrow;
#pragma unroll
        for (int ni = 0; ni < 4; ++ni) orow[ni * 16] = acc[mi][ni][reg] + bcol[ni];
      }
    }
  } else {
    const int which = n0 >> 12;               // 0=q 1=k 2=v (256-tile never straddles)
    unsigned short* dst = (which == 0) ? Qo : (which == 1) ? Ko : Vo;
    const int nn0 = n0 & 4095;
    const bool ropeW = (which < 2) && ((wn & 1) == 0);  // ni=0/1 hold the rotary pair
    const float invf = exp2f(-(float)lrow * 0.8304820237218406f); // 10000^(-lrow/16)
#pragma unroll
    for (int mi = 0; mi < 4; ++mi) {
      int sBase = m0 + wm * 64 + mi * 16 + rb;
#pragma unroll
      for (int reg = 0; reg < 4; ++reg) {
        int s = sBase + reg;
        float v[4];
#pragma unroll
        for (int ni = 0; ni < 4; ++ni) v[ni] = acc[mi][ni][reg] + bcol[ni];
        if (ropeW) {
          float ang = (float)posids[s] * invf;
          float sn, cs;
          sincosf(ang, &sn, &cs);
          float x1 = v[0], x2 = v[1];
          v[0] = x1 * cs - x2 * sn;
          v[1] = x2 * cs + x1 * sn;
        }
#pragma unroll
        for (int ni = 0; ni < 4; ++ni) {
          int n = nn0 + wn * 64 + ni * 16 + lrow;
          int h = n >> 7, d = n & 127;
          dst[((size_t)(h * SEQ + s) << 7) + d] = f2bf(v[ni]);
        }
      }
    }
  }
}

// ---------------- fused causal attention (unchanged) ----------------
__global__ __launch_bounds__(256, 2)
void k_attn(const unsigned short* __restrict__ Q, const unsigned short* __restrict__ Kk,
            const unsigned short* __restrict__ VT, unsigned short* __restrict__ O) {
  __shared__ unsigned short Kls[2][64 * 128];
  __shared__ unsigned short Vls[128 * 64];
  __shared__ unsigned short Pls[4][32 * 64];
  const int tid = threadIdx.x, lane = tid & 63, wave = tid >> 6;
  const int head = blockIdx.x >> 4, qb = blockIdx.x & 15;
  const int q0 = qb * 128;
  const int q0w = q0 + wave * 32;
  const int lrow = lane & 15;
  const int lkb = (lane >> 4) << 4;
  const int swzl = (lrow & 7) << 4;
  const int rb = (lane >> 4) << 2;
  const unsigned short* Qh = Q + (size_t)head * SEQ * HD;
  const char* Kg = (const char*)(Kk + (size_t)head * SEQ * HD);
  const char* Vg = (const char*)(VT + (size_t)head * HD * SEQ);

  const int tKr = tid >> 4;
  const int tKsw = ((tid & 15) << 4) ^ ((tKr & 7) << 4);
  const int tVr = tid >> 3;
  const int tVsw = ((tid & 7) << 4) ^ ((tVr & 7) << 4);
  char* kD0 = (char*)&Kls[0][0] + tid * 16;
  char* kD1 = (char*)&Kls[1][0] + tid * 16;
  char* vD = (char*)&Vls[0] + tid * 16;

  bf16x8 qf[2][4];
#pragma unroll
  for (int mi = 0; mi < 2; ++mi) {
    const char* qrow = (const char*)(Qh + (size_t)(q0w + mi * 16 + lrow) * HD);
#pragma unroll
    for (int kk = 0; kk < 4; ++kk) qf[mi][kk] = *(const bf16x8*)(qrow + kk * 64 + lkb);
  }

  float mrun[2][4], lrun[2][4];
#pragma unroll
  for (int mi = 0; mi < 2; ++mi)
#pragma unroll
    for (int r = 0; r < 4; ++r) { mrun[mi][r] = -3e38f; lrun[mi][r] = 0.f; }
  f32x4 o[2][8] = {};

  const int nt = (q0 >> 6) + 2;

#pragma unroll
  for (int j = 0; j < 4; ++j)
    gl_lds16(Kg + (size_t)(j * 16 + tKr) * 256 + tKsw, kD0 + j * 4096);
  asm volatile("s_waitcnt vmcnt(0)" ::: "memory");
  __builtin_amdgcn_s_barrier();
  __builtin_amdgcn_sched_barrier(0);

  for (int t = 0; t < nt; ++t) {
    const int kv0 = t * 64;
    const char* kCur = (t & 1) ? (const char*)&Kls[1][0] : (const char*)&Kls[0][0];
    char* kNxt = (t & 1) ? kD0 : kD1;
    const bool more = (t + 1 < nt);

#pragma unroll
    for (int j = 0; j < 4; ++j)
      gl_lds16(Vg + (size_t)(j * 32 + tVr) * (SEQ * 2) + kv0 * 2 + tVsw, vD + j * 4096);
    if (more) {
#pragma unroll
      for (int j = 0; j < 4; ++j)
        gl_lds16(Kg + (size_t)(kv0 + 64 + j * 16 + tKr) * 256 + tKsw, kNxt + j * 4096);
    }

    f32x4 sfr[2][4] = {};
#pragma unroll
    for (int kk = 0; kk < 4; ++kk) {
#pragma unroll
      for (int ni = 0; ni < 4; ++ni) {
        bf16x8 kf = *(const bf16x8*)(kCur + (ni * 16 + lrow) * 256 + ((kk * 64 + lkb) ^ swzl));
        sfr[0][ni] = __builtin_amdgcn_mfma_f32_16x16x32_bf16(qf[0][kk], kf, sfr[0][ni], 0, 0, 0);
        sfr[1][ni] = __builtin_amdgcn_mfma_f32_16x16x32_bf16(qf[1][kk], kf, sfr[1][ni], 0, 0, 0);
      }
    }

#pragma unroll
    for (int mi = 0; mi < 2; ++mi) {
      float pm[4];
#pragma unroll
      for (int reg = 0; reg < 4; ++reg) {
        int qr = q0w + mi * 16 + rb + reg;
        float mx = -3e38f;
#pragma unroll
        for (int ni = 0; ni < 4; ++ni) {
          int col = kv0 + ni * 16 + lrow;
          float v = sfr[mi][ni][reg] * ATT_SCALE;
          if (col > qr) v = -3e38f;
          sfr[mi][ni][reg] = v;
          mx = fmaxf(mx, v);
        }
        pm[reg] = mx;
      }
#pragma unroll
      for (int x = 1; x < 16; x <<= 1)
#pragma unroll
        for (int reg = 0; reg < 4; ++reg) pm[reg] = fmaxf(pm[reg], __shfl_xor(pm[reg], x));
      float corr[4], rs[4];
#pragma unroll
      for (int reg = 0; reg < 4; ++reg) {
        float mn = fmaxf(mrun[mi][reg], pm[reg]);
        corr[reg] = exp2f((mrun[mi][reg] - mn) * L2E);
        mrun[mi][reg] = mn;
        float a = 0.f;
#pragma unroll
        for (int ni = 0; ni < 4; ++ni) {
          float p = exp2f((sfr[mi][ni][reg] - mn) * L2E);
          sfr[mi][ni][reg] = p;
          a += p;
        }
        rs[reg] = a;
      }
#pragma unroll
      for (int x = 1; x < 16; x <<= 1)
#pragma unroll
        for (int reg = 0; reg < 4; ++reg) rs[reg] += __shfl_xor(rs[reg], x);
#pragma unroll
      for (int reg = 0; reg < 4; ++reg) lrun[mi][reg] = lrun[mi][reg] * corr[reg] + rs[reg];
#pragma unroll
      for (int n2 = 0; n2 < 8; ++n2)
#pragma unroll
        for (int reg = 0; reg < 4; ++reg) o[mi][n2][reg] *= corr[reg];
    }

    unsigned short* pw = &Pls[wave][0];
#pragma unroll
    for (int mi = 0; mi < 2; ++mi)
#pragma unroll
      for (int reg = 0; reg < 4; ++reg) {
        int row = mi * 16 + rb + reg;
        int sw = (row & 7) << 4;
#pragma unroll
        for (int ni = 0; ni < 4; ++ni) {
          int b = (ni * 32 + lrow * 2) ^ sw;
          *(unsigned short*)((char*)pw + row * 128 + b) = f2bf(sfr[mi][ni][reg]);
        }
      }
    asm volatile("s_waitcnt lgkmcnt(0)" ::: "memory");
    __builtin_amdgcn_sched_barrier(0);

    if (more) asm volatile("s_waitcnt vmcnt(4)" ::: "memory");
    else      asm volatile("s_waitcnt vmcnt(0)" ::: "memory");
    __builtin_amdgcn_s_barrier();
    __builtin_amdgcn_sched_barrier(0);

#pragma unroll
    for (int kk2 = 0; kk2 < 2; ++kk2) {
      bf16x8 pa0 = *(const bf16x8*)((const char*)pw + lrow * 128 + ((kk2 * 64 + lkb) ^ swzl));
      bf16x8 pa1 = *(const bf16x8*)((const char*)pw + (16 + lrow) * 128 + ((kk2 * 64 + lkb) ^ swzl));
#pragma unroll
      for (int n2 = 0; n2 < 8; ++n2) {
        bf16x8 vf = *(const bf16x8*)((const char*)&Vls[0] + (n2 * 16 + lrow) * 128 + ((kk2 * 64 + lkb) ^ swzl));
        o[0][n2] = __builtin_amdgcn_mfma_f32_16x16x32_bf16(pa0, vf, o[0][n2], 0, 0, 0);
        o[1][n2] = __builtin_amdgcn_mfma_f32_16x16x32_bf16(pa1, vf, o[1][n2], 0, 0, 0);
      }
    }

    asm volatile("s_waitcnt vmcnt(0)" ::: "memory");
    __builtin_amdgcn_s_barrier();
    __builtin_amdgcn_sched_barrier(0);
  }

#pragma unroll
  for (int mi = 0; mi < 2; ++mi)
#pragma unroll
    for (int reg = 0; reg < 4; ++reg) {
      int s = q0w + mi * 16 + rb + reg;
      float inv = 1.f / lrun[mi][reg];
      unsigned short* orow = O + (size_t)s * HID + head * HD + lrow;
#pragma unroll
      for (int n2 = 0; n2 < 8; ++n2) orow[n2 * 16] = f2bf(o[mi][n2][reg] * inv);
    }
}

extern "C" void kernel_launch(void* const* d_in, const int* in_sizes, int n_in,
                              void* d_out, int out_size, void* d_ws, size_t ws_size,
                              hipStream_t stream) {
  const int* pos = (const int*)d_in[0];
  const float* hidden = (const float*)d_in[1];
  const float* wqkv = (const float*)d_in[2];
  const float* bqkv = (const float*)d_in[3];
  const float* wdense = (const float*)d_in[4];
  const float* bdense = (const float*)d_in[5];
  float* out = (float*)d_out;

  unsigned short* w16 = (unsigned short*)d_ws;
  unsigned short* hiddenB = w16;                               // [S][H]
  unsigned short* wqkvT = hiddenB + (size_t)SEQ * HID;         // [3H][H]
  unsigned short* wdT = wqkvT + (size_t)3 * HID * HID;         // [H][H]
  unsigned short* Qb = wdT + (size_t)HID * HID;                // [h][s][d]
  unsigned short* Kb = Qb + (size_t)SEQ * HID;
  unsigned short* Vb = Kb + (size_t)SEQ * HID;
  unsigned short* VTb = Vb + (size_t)SEQ * HID;                // [h][d][s]
  unsigned short* AOb = VTb + (size_t)SEQ * HID;               // [s][h*d]

  k_conv_hidden<<<(SEQ * HID) / (8 * 256), 256, 0, stream>>>(hidden, hiddenB);
  k_transpose_w<<<(HID / 64) * (3 * HID / 64), 256, 0, stream>>>(wqkv, wqkvT, HID, 3 * HID);
  k_transpose_w<<<(HID / 64) * (HID / 64), 256, 0, stream>>>(wdense, wdT, HID, HID);
  k_gemm8<1><<<(SEQ / 128) * (3 * HID / 256), 512, 0, stream>>>(hiddenB, wqkvT, bqkv, pos,
                                                                nullptr, Qb, Kb, Vb, 3 * HID);
  k_transpose_v<<<NH * (SEQ / 64) * (HD / 64), 256, 0, stream>>>(Vb, VTb);
  k_attn<<<NH * (SEQ / 128), 256, 0, stream>>>(Qb, Kb, VTb, AOb);
  k_gemm8<0><<<(SEQ / 128) * (HID / 256), 512, 0, stream>>>(AOb, wdT, bdense, nullptr, out,
                                                            nullptr, nullptr, nullptr, HID);
}